// Round 5
// baseline (2700.493 us; speedup 1.0000x reference)
//
#include <hip/hip_runtime.h>
#include <cstdint>

// Autoregressive LSTM, MI355X. BISECT ROUND: round-3's exact arithmetic path
// (builtin fdot2, __shfl quad broadcast, __shfl_xor dense reduce) with the
// round-4 occupancy restructure only: 512 blocks x 512 threads, ONE batch row
// per block, 2 independent blocks/CU (4 waves/SIMD). Per-row math is
// bit-identical to the passing round-3 kernel.

#define T_SEQ 1024
#define N_F   64
#define N_H   128

typedef _Float16 h2f __attribute__((ext_vector_type(2)));

__device__ __forceinline__ float sigf(float x) {
    return __builtin_amdgcn_rcpf(1.f + __expf(-x));
}
__device__ __forceinline__ float tanh_fast(float x) {
    return 1.f - 2.f * __builtin_amdgcn_rcpf(1.f + __expf(2.f * x));
}

#if __has_builtin(__builtin_amdgcn_fdot2)
__device__ __forceinline__ float fdot2(uint32_t a, uint32_t b, float c) {
    return __builtin_amdgcn_fdot2(__builtin_bit_cast(h2f, a),
                                  __builtin_bit_cast(h2f, b), c, false);
}
#else
__device__ __forceinline__ float fdot2(uint32_t a, uint32_t b, float c) {
    h2f av = __builtin_bit_cast(h2f, a), bv = __builtin_bit_cast(h2f, b);
    return fmaf((float)av.x, (float)bv.x, fmaf((float)av.y, (float)bv.y, c));
}
#endif

__device__ __forceinline__ uint32_t packh2(float a, float b) {
    h2f v; v.x = (_Float16)a; v.y = (_Float16)b;
    return __builtin_bit_cast(uint32_t, v);
}

__global__ __launch_bounds__(512, 4)
void lstm_autoreg(const float* __restrict__ x,
                  const int*   __restrict__ avail,
                  const int*   __restrict__ pred,
                  const float* __restrict__ W_ih,
                  const float* __restrict__ W_hh,
                  const float* __restrict__ b_ih,
                  const float* __restrict__ b_hh,
                  const float* __restrict__ W_den,
                  const float* __restrict__ b_den,
                  const float* __restrict__ init_ch,
                  float*       __restrict__ out)
{
    __shared__ __align__(16) uint32_t xT[64][32];    // [tmod][fpair] f16x2, 8KB
    __shared__ __align__(16) float    obuf[N_F][36]; // out staging, 9KB
    __shared__ __align__(16) uint32_t h2buf[2][64];  // [buf][jpair] f16x2
    __shared__ __align__(16) uint32_t pv2[32];       // prev out f16 pairs
    __shared__ int red[8];

    const int tid  = threadIdx.x;
    const int lane = tid & 63;
    const int r    = blockIdx.x;          // one batch row per block

    // ---- max_idx = min(max(predict_len), T): 512 threads == BATCH ----
    int pv = pred[tid];
    #pragma unroll
    for (int m = 1; m < 64; m <<= 1) pv = max(pv, __shfl_xor(pv, m));
    if (lane == 0) red[tid >> 6] = pv;
    __syncthreads();
    int max_idx = red[0];
    #pragma unroll
    for (int w = 1; w < 8; ++w) max_idx = max(max_idx, red[w]);
    if (max_idx > T_SEQ) max_idx = T_SEQ;

    // ---- role indices (identical to round 3) ----
    const int gt = tid & 3;          // gate type (i,f,g,o)
    const int j  = tid >> 2;         // hidden unit [0,128)
    const int g  = gt * N_H + j;     // weight row
    const int of = tid >> 3;         // dense feature [0,64)
    const int oc = tid & 7;          // dense K-chunk [0,8)

    // ---- weights -> packed f16 in VGPRs (104 regs) ----
    uint32_t wih[32], whh[64], wdn[8];
    {
        const float* p = W_ih + g * N_F;
        #pragma unroll
        for (int i = 0; i < 32; ++i) wih[i] = packh2(p[2*i], p[2*i+1]);
        const float* q = W_hh + g * N_H;
        #pragma unroll
        for (int i = 0; i < 64; ++i) whh[i] = packh2(q[2*i], q[2*i+1]);
        const float* rr = W_den + of * N_H + oc * 16;
        #pragma unroll
        for (int i = 0; i < 8; ++i) wdn[i] = packh2(rr[2*i], rr[2*i+1]);
    }
    #pragma unroll
    for (int i = 0; i < 32; ++i) asm volatile("" : "+v"(wih[i]));
    #pragma unroll
    for (int i = 0; i < 64; ++i) asm volatile("" : "+v"(whh[i]));
    #pragma unroll
    for (int i = 0; i < 8; ++i)  asm volatile("" : "+v"(wdn[i]));

    const float bacc = b_ih[g] + b_hh[g];
    const float bden = b_den[of];
    const int av = avail[r], pr = pred[r];

    // ---- state init ----
    float c = init_ch[j];                               // c0 = init_ch[:H]
    if (tid < 64)
        h2buf[0][tid] = packh2(init_ch[N_H + 2*tid], init_ch[N_H + 2*tid + 1]);
    __syncthreads();

    for (int t = 0; t < T_SEQ; ++t) {
        // ---- stage 64 timesteps of x, transposed, f32 -> f16 ----
        if ((t & 63) == 0) {
            #pragma unroll
            for (int k = 0; k < 2; ++k) {
                int idx = tid + k * 512;                // 1024 float4
                int tq = idx & 15, f = idx >> 4;
                const float4 v = *(const float4*)
                    (x + ((size_t)r * N_F + f) * T_SEQ + t + tq * 4);
                _Float16* dst = (_Float16*)&xT[0][0];
                dst[(tq*4+0)*64 + f] = (_Float16)v.x;
                dst[(tq*4+1)*64 + f] = (_Float16)v.y;
                dst[(tq*4+2)*64 + f] = (_Float16)v.z;
                dst[(tq*4+3)*64 + f] = (_Float16)v.w;
            }
            __syncthreads();
        }
        const int rb = t & 1, wb = rb ^ 1;
        const int tm = t & 63;

        // ---- phase A: gates + cell (round-3 chain structure) ----
        const bool fb = (t >= av) & (t < pr) & (t > 0);
        const uint32_t* xs = fb ? pv2 : &xT[tm][0];
        const uint32_t* hb = h2buf[rb];

        float A0 = bacc, B0 = 0.f;
        #pragma unroll
        for (int i = 0; i < 32; ++i) A0 = fdot2(wih[i], xs[i], A0);
        #pragma unroll
        for (int i = 0; i < 64; ++i) B0 = fdot2(whh[i], hb[i], B0);
        float g0 = A0 + B0;

        // quad exchange via __shfl (round-3 path)
        const int qb = lane & ~3;
        float gi = __shfl(g0, qb + 0), gf = __shfl(g0, qb + 1);
        float gg = __shfl(g0, qb + 2), go = __shfl(g0, qb + 3);

        c = sigf(gf) * c + sigf(gi) * tanh_fast(gg);
        float h = sigf(go) * tanh_fast(c);
        if (gt == 0)
            ((_Float16*)&h2buf[wb][0])[j] = (_Float16)h;
        __syncthreads();

        // ---- phase B: dense out (8 threads per feature, round-3 path) ----
        const uint32_t* hq = &h2buf[wb][oc * 8];
        float d = 0.f;
        #pragma unroll
        for (int i = 0; i < 8; ++i) d = fdot2(wdn[i], hq[i], d);
        d += __shfl_xor(d, 1);
        d += __shfl_xor(d, 2);
        d += __shfl_xor(d, 4);
        if (oc == 0) {
            float o = d + bden;
            ((_Float16*)pv2)[of] = (_Float16)o;       // feedback (unmasked)
            obuf[of][t & 31] = (t < max_idx) ? o : 0.f;
        }

        // ---- flush outputs, coalesced, every 32 steps ----
        if ((t & 31) == 31) {
            __syncthreads();
            int f = tid >> 3, tq = tid & 7;           // 512 float4, 1 per thread
            float4 v = *(const float4*)&obuf[f][tq * 4];
            *(float4*)(out + ((size_t)r * N_F + f) * T_SEQ + (t & ~31) + tq * 4) = v;
        }
        __syncthreads();
    }
}

extern "C" void kernel_launch(void* const* d_in, const int* in_sizes, int n_in,
                              void* d_out, int out_size, void* d_ws, size_t ws_size,
                              hipStream_t stream) {
    const float* x      = (const float*)d_in[0];
    const int*   avail  = (const int*)  d_in[1];
    const int*   pred   = (const int*)  d_in[2];
    const float* W_ih   = (const float*)d_in[3];
    const float* W_hh   = (const float*)d_in[4];
    const float* b_ih   = (const float*)d_in[5];
    const float* b_hh   = (const float*)d_in[6];
    const float* W_den  = (const float*)d_in[7];
    const float* b_den  = (const float*)d_in[8];
    const float* initch = (const float*)d_in[9];
    float* out = (float*)d_out;

    hipLaunchKernelGGL(lstm_autoreg, dim3(512), dim3(512), 0, stream,
                       x, avail, pred, W_ih, W_hh, b_ih, b_hh, W_den, b_den,
                       initch, out);
}